// Round 16
// baseline (315.183 us; speedup 1.0000x reference)
//
#include <hip/hip_runtime.h>
#include <hip/hip_bf16.h>

#define NEG_SLOPE 0.2f

typedef __attribute__((ext_vector_type(8))) short  bf16x8;
typedef __attribute__((ext_vector_type(8))) unsigned short u16x8;
typedef __attribute__((ext_vector_type(4))) unsigned short u16x4;
typedef __attribute__((ext_vector_type(4))) float  f32x4;

static __device__ __forceinline__ ushort f2bf(float f) {
    union { float f; unsigned int u; } c; c.f = f;
    unsigned int r = c.u + 0x7fffu + ((c.u >> 16) & 1u);   // round-to-nearest-even
    return (ushort)(r >> 16);
}
static __device__ __forceinline__ float bf2f(ushort u) {
    union { unsigned int u; float f; } c; c.u = ((unsigned int)u) << 16;
    return c.f;
}

// ---------------- zero cnt ----------------
__global__ __launch_bounds__(256) void zero_k(int4* __restrict__ p, int n4)
{
    int t = blockIdx.x * 256 + threadIdx.x;
    if (t < n4) p[t] = make_int4(0, 0, 0, 0);
}

// ---------------- phase1: prep_w1 (blocks 0..127) + hist (rest), fused ----------------
__global__ __launch_bounds__(256) void phase1_k(
    const float* __restrict__ W, ushort* __restrict__ W1T,
    const int* __restrict__ ei, int* __restrict__ cnt, int* __restrict__ slot, int E)
{
    if (blockIdx.x < 128) {
        int idx = blockIdx.x * 256 + threadIdx.x;      // 32768 = 64*512 exactly
        int c = idx >> 9, k = idx & 511;
        W1T[idx] = f2bf(W[k * 64 + c]);
    } else {
        int t = (blockIdx.x - 128) * 256 + threadIdx.x;
        if (t < E) slot[t] = atomicAdd(&cnt[ei[E + t]], 1);
    }
}

#define SCAN_B 256
#define SCAN_T 256

__global__ __launch_bounds__(SCAN_T) void scan_a(const int* __restrict__ cnt, int* __restrict__ bsum, int n)
{
    __shared__ int sh[SCAN_T];
    const int tid = threadIdx.x;
    const int per = (n + SCAN_B * SCAN_T - 1) / (SCAN_B * SCAN_T);
    const int lo = (blockIdx.x * SCAN_T + tid) * per;
    const int hi = min(n, lo + per);
    int s = 0;
    for (int i = lo; i < hi; ++i) s += cnt[i];
    sh[tid] = s;
    __syncthreads();
    #pragma unroll
    for (int o = SCAN_T / 2; o; o >>= 1) {
        if (tid < o) sh[tid] += sh[tid + o];
        __syncthreads();
    }
    if (tid == 0) bsum[blockIdx.x] = sh[0];
}

__global__ __launch_bounds__(SCAN_T) void scan_b(
    const int* __restrict__ cnt, const int* __restrict__ bsum,
    int* __restrict__ rowptr, int n, int E)
{
    __shared__ int sb[SCAN_B];
    __shared__ int sh[SCAN_T];
    const int tid = threadIdx.x;
    sb[tid] = bsum[tid];
    __syncthreads();
    #pragma unroll
    for (int o = 1; o < SCAN_B; o <<= 1) {
        int v = (tid >= o) ? sb[tid - o] : 0;
        __syncthreads();
        sb[tid] += v;
        __syncthreads();
    }
    const int boff = (blockIdx.x == 0) ? 0 : sb[blockIdx.x - 1];

    const int per = (n + SCAN_B * SCAN_T - 1) / (SCAN_B * SCAN_T);
    const int lo = (blockIdx.x * SCAN_T + tid) * per;
    const int hi = min(n, lo + per);
    int s = 0;
    for (int i = lo; i < hi; ++i) s += cnt[i];
    sh[tid] = s;
    __syncthreads();
    #pragma unroll
    for (int o = 1; o < SCAN_T; o <<= 1) {
        int v = (tid >= o) ? sh[tid - o] : 0;
        __syncthreads();
        sh[tid] += v;
        __syncthreads();
    }
    int excl = boff + ((tid == 0) ? 0 : sh[tid - 1]);
    for (int i = lo; i < hi; ++i) { rowptr[i] = excl; excl += cnt[i]; }
    if (blockIdx.x == 0 && tid == 0) rowptr[n] = E;
}

__global__ __launch_bounds__(256) void scatter_k(
    const int* __restrict__ ei, const int* __restrict__ rowptr,
    const int* __restrict__ slot, int* __restrict__ ssrc, int E)
{
    int t = blockIdx.x * blockDim.x + threadIdx.x;
    if (t >= E) return;
    int d = ei[E + t];
    ssrc[rowptr[d] + slot[t]] = ei[t];
}

// ---------------- GEMM1: NO LDS — B-fragments straight from L2-resident W1T ----------
// 8 waves x 16-row strip (128 rows/block); zero barriers; VGPR target <=64 -> 8 waves/SIMD
__global__ __launch_bounds__(512) void gemm1_mfma(
    const float* __restrict__ x, const ushort* __restrict__ W1T,
    const float* __restrict__ att_src, const float* __restrict__ att_dst,
    ushort* __restrict__ h1b, float* __restrict__ asrc, float* __restrict__ adst, int n)
{
    const int t    = threadIdx.x;
    const int lane = t & 63;
    const int wv   = t >> 6;        // 0..7
    const int rb   = blockIdx.x * 128;
    const int m    = lane & 15;
    const int kg   = lane >> 4;

    const int arow  = rb + wv * 16 + m;
    const int arowc = min(arow, n - 1);
    const float* xp = x + (size_t)arowc * 512 + kg * 8;
    // B base for this lane: row (t4*16+m), k-offset kg*8
    const ushort* wp = W1T + (size_t)m * 512 + kg * 8;

    f32x4 acc[4] = {};

    // depth-2 register prefetch on x; B direct from global each iter (L2-hit)
    float4 lo0 = *(const float4*)(xp);
    float4 hi0 = *(const float4*)(xp + 4);
    float4 lo1 = *(const float4*)(xp + 32);
    float4 hi1 = *(const float4*)(xp + 36);
    #pragma unroll
    for (int k32 = 0; k32 < 16; ++k32) {
        float4 nlo = {}, nhi = {};
        if (k32 < 14) {
            nlo = *(const float4*)(xp + (k32 + 2) * 32);
            nhi = *(const float4*)(xp + (k32 + 2) * 32 + 4);
        }
        u16x8 a;
        a[0] = f2bf(lo0.x); a[1] = f2bf(lo0.y); a[2] = f2bf(lo0.z); a[3] = f2bf(lo0.w);
        a[4] = f2bf(hi0.x); a[5] = f2bf(hi0.y); a[6] = f2bf(hi0.z); a[7] = f2bf(hi0.w);
        bf16x8 af = *(bf16x8*)&a;
        #pragma unroll
        for (int t4 = 0; t4 < 4; ++t4) {
            bf16x8 bfr = *(const bf16x8*)(wp + (size_t)t4 * 16 * 512 + k32 * 32);
            acc[t4] = __builtin_amdgcn_mfma_f32_16x16x32_bf16(af, bfr, acc[t4], 0, 0, 0);
        }
        lo0 = lo1; hi0 = hi1; lo1 = nlo; hi1 = nhi;
    }

    // epilogue: C/D col=m, row=kg*4+i; fused per-head att reductions
    #pragma unroll
    for (int t4 = 0; t4 < 4; ++t4) {
        const float as_w = att_src[t4 * 16 + m];
        const float ad_w = att_dst[t4 * 16 + m];
        #pragma unroll
        for (int i = 0; i < 4; ++i) {
            int gr = rb + wv * 16 + kg * 4 + i;
            float v = acc[t4][i];
            float ps = v * as_w, pd = v * ad_w;
            ps += __shfl_xor(ps, 1); pd += __shfl_xor(pd, 1);
            ps += __shfl_xor(ps, 2); pd += __shfl_xor(pd, 2);
            ps += __shfl_xor(ps, 4); pd += __shfl_xor(pd, 4);
            if (gr < n) {
                h1b[(size_t)gr * 64 + t4 * 16 + m] = f2bf(v);
                if ((m & 7) == 0) {
                    int h = t4 * 2 + (m >> 3);
                    asrc[gr * 8 + h] = ps;
                    adst[gr * 8 + h] = pd;
                }
            }
        }
    }
}

// ---------------- layer1 aggregate + ELU + GEMM2 + att2 ----------------
__global__ __launch_bounds__(256) void agg1_k(
    const int* __restrict__ rowptr, const int* __restrict__ ssrc,
    const float* __restrict__ asrc1, const float* __restrict__ adst1,
    const ushort* __restrict__ h1b, const float* __restrict__ b1,
    const float* __restrict__ W2, const float* __restrict__ att_src2, const float* __restrict__ att_dst2,
    ushort* __restrict__ h2b, float* __restrict__ asrc2, float* __restrict__ adst2, int n)
{
    __shared__ float Ws2[64 * 17];
    __shared__ float sv[4][64];
    const int t = threadIdx.x;
    #pragma unroll
    for (int k = 0; k < 4; ++k) {
        int idx = t + k * 256;
        Ws2[(idx >> 4) * 17 + (idx & 15)] = W2[idx];
    }
    __syncthreads();

    const int wv = t >> 6;
    const int j  = t & 63;
    const int g  = j >> 3;
    const int h  = j & 7;
    const int node = blockIdx.x * 4 + wv;
    const bool active = node < n;

    if (active) {
        const int d = node;
        const int start = rowptr[d], end = rowptr[d + 1];
        const float adsth = adst1[d * 8 + h];
        float acc0[8] = {}, acc1[8] = {};
        float dsum0 = 0.f, dsum1 = 0.f;
        for (int base = start - 1; base < end; base += 16) {
            int i0 = base + g;
            int i1 = i0 + 8;
            if (i0 < end) {
                int s = (i0 < start) ? d : ssrc[i0];
                float e = asrc1[s * 8 + h] + adsth;
                e = e > 0.f ? e : NEG_SLOPE * e;
                float ex = __expf(e);
                dsum0 += ex;
                u16x8 hv = *(const u16x8*)(h1b + (size_t)s * 64 + h * 8);
                #pragma unroll
                for (int c = 0; c < 8; ++c) acc0[c] += ex * bf2f(hv[c]);
            }
            if (i1 < end) {
                int s = ssrc[i1];
                float e = asrc1[s * 8 + h] + adsth;
                e = e > 0.f ? e : NEG_SLOPE * e;
                float ex = __expf(e);
                dsum1 += ex;
                u16x8 hv = *(const u16x8*)(h1b + (size_t)s * 64 + h * 8);
                #pragma unroll
                for (int c = 0; c < 8; ++c) acc1[c] += ex * bf2f(hv[c]);
            }
        }
        float dsum = dsum0 + dsum1;
        float acc[8];
        #pragma unroll
        for (int c = 0; c < 8; ++c) acc[c] = acc0[c] + acc1[c];
        #pragma unroll
        for (int o = 8; o < 64; o <<= 1) {
            dsum += __shfl_xor(dsum, o);
            #pragma unroll
            for (int c = 0; c < 8; ++c) acc[c] += __shfl_xor(acc[c], o);
        }
        if (g == 0) {
            float den = dsum + 1e-16f;
            #pragma unroll
            for (int c = 0; c < 8; ++c) {
                float v = acc[c] / den + b1[h * 8 + c];
                v = v > 0.f ? v : (__expf(v) - 1.f);   // ELU
                sv[wv][h * 8 + c] = v;
            }
        }
    }
    __syncthreads();

    if (active) {
        const int c = j & 15, q = j >> 4;
        float p = 0.f;
        #pragma unroll
        for (int r = 0; r < 16; ++r)
            p += sv[wv][q * 16 + r] * Ws2[(q * 16 + r) * 17 + c];
        p += __shfl_xor(p, 16);
        p += __shfl_xor(p, 32);
        if (j < 16) h2b[(size_t)node * 16 + j] = f2bf(p);
        float as2 = p * att_src2[c];
        float ad2 = p * att_dst2[c];
        #pragma unroll
        for (int o = 1; o < 16; o <<= 1) { as2 += __shfl_xor(as2, o, 16); ad2 += __shfl_xor(ad2, o, 16); }
        if (j == 0) { asrc2[node] = as2; adst2[node] = ad2; }
    }
}

// ---------------- layer2 aggregate + log_softmax ----------------
__global__ __launch_bounds__(256) void agg2_k(
    const int* __restrict__ rowptr, const int* __restrict__ ssrc,
    const float* __restrict__ asrc2, const float* __restrict__ adst2,
    const ushort* __restrict__ h2b, const float* __restrict__ b2,
    float* __restrict__ out, int n)
{
    const int t = threadIdx.x;
    const int node = blockIdx.x * 4 + (t >> 6);
    if (node >= n) return;
    const int j = t & 63;
    const int g = j >> 2;
    const int q = j & 3;
    const int d = node;
    const int start = rowptr[d], end = rowptr[d + 1];
    const float adst_d = adst2[d];

    float acc0[4] = {}, acc1[4] = {};
    float dsum0 = 0.f, dsum1 = 0.f;
    for (int base = start - 1; base < end; base += 32) {
        int i0 = base + g;
        int i1 = i0 + 16;
        if (i0 < end) {
            int s = (i0 < start) ? d : ssrc[i0];
            float e = asrc2[s] + adst_d;
            e = e > 0.f ? e : NEG_SLOPE * e;
            float ex = __expf(e);
            dsum0 += ex;
            u16x4 hv = *(const u16x4*)(h2b + (size_t)s * 16 + q * 4);
            #pragma unroll
            for (int c = 0; c < 4; ++c) acc0[c] += ex * bf2f(hv[c]);
        }
        if (i1 < end) {
            int s = ssrc[i1];
            float e = asrc2[s] + adst_d;
            e = e > 0.f ? e : NEG_SLOPE * e;
            float ex = __expf(e);
            dsum1 += ex;
            u16x4 hv = *(const u16x4*)(h2b + (size_t)s * 16 + q * 4);
            #pragma unroll
            for (int c = 0; c < 4; ++c) acc1[c] += ex * bf2f(hv[c]);
        }
    }
    float dsum = dsum0 + dsum1;
    float acc[4];
    #pragma unroll
    for (int c = 0; c < 4; ++c) acc[c] = acc0[c] + acc1[c];
    #pragma unroll
    for (int o = 4; o < 64; o <<= 1) {
        dsum += __shfl_xor(dsum, o);
        #pragma unroll
        for (int c = 0; c < 4; ++c) acc[c] += __shfl_xor(acc[c], o);
    }

    const float den = dsum + 1e-16f;
    float v[4];
    float m = -1e30f;
    #pragma unroll
    for (int c = 0; c < 4; ++c) {
        v[c] = acc[c] / den + b2[q * 4 + c];
        m = fmaxf(m, v[c]);
    }
    m = fmaxf(m, __shfl_xor(m, 1));
    m = fmaxf(m, __shfl_xor(m, 2));
    float s2 = 0.f;
    #pragma unroll
    for (int c = 0; c < 4; ++c) s2 += __expf(v[c] - m);
    s2 += __shfl_xor(s2, 1);
    s2 += __shfl_xor(s2, 2);
    const float lse = m + logf(s2);
    if (j < 4) {
        float4 o4 = make_float4(v[0] - lse, v[1] - lse, v[2] - lse, v[3] - lse);
        *(float4*)(out + (size_t)d * 16 + q * 4) = o4;
    }
}

static inline size_t align_up(size_t v, size_t a) { return (v + a - 1) & ~(a - 1); }

extern "C" void kernel_launch(void* const* d_in, const int* in_sizes, int n_in,
                              void* d_out, int out_size, void* d_ws, size_t ws_size,
                              hipStream_t stream) {
    const float* x        = (const float*)d_in[0];
    const int*   ei       = (const int*)d_in[1];
    const float* W1       = (const float*)d_in[2];
    const float* att_src1 = (const float*)d_in[3];
    const float* att_dst1 = (const float*)d_in[4];
    const float* b1       = (const float*)d_in[5];
    const float* W2       = (const float*)d_in[6];
    const float* att_src2 = (const float*)d_in[7];
    const float* att_dst2 = (const float*)d_in[8];
    const float* b2       = (const float*)d_in[9];
    float* out = (float*)d_out;

    const int n = in_sizes[0] / 512;
    const int E = in_sizes[1] / 2;

    // 64B-aligned workspace layout
    char* base = (char*)d_ws;
    size_t off = 0;
    ushort* h1b   = (ushort*)(base + off); off = align_up(off + (size_t)128 * n, 64);
    ushort* h2b   = (ushort*)(base + off); off = align_up(off + (size_t)32 * n, 64);
    float*  asrc1 = (float*) (base + off); off = align_up(off + (size_t)32 * n, 64);
    float*  adst1 = (float*) (base + off); off = align_up(off + (size_t)32 * n, 64);
    float*  asrc2 = (float*) (base + off); off = align_up(off + (size_t)4 * n, 64);
    float*  adst2 = (float*) (base + off); off = align_up(off + (size_t)4 * n, 64);
    ushort* W1T   = (ushort*)(base + off); off = align_up(off + (size_t)65536, 64);
    int*    rowptr= (int*)   (base + off); off = align_up(off + (size_t)4 * (n + 1), 64);
    int*    cnt   = (int*)   (base + off); off = align_up(off + (size_t)4 * n, 64);
    int*    bsum  = (int*)   (base + off); off = align_up(off + (size_t)1024, 64);
    int*    slot  = (int*)   (base + off); off = align_up(off + (size_t)4 * E, 64);
    int*    ssrc  = (int*)   (base + off);

    const int n4 = (n + 3) / 4;
    zero_k<<<(n4 + 255) / 256, 256, 0, stream>>>((int4*)cnt, n4);

    phase1_k<<<128 + (E + 255) / 256, 256, 0, stream>>>(W1, W1T, ei, cnt, slot, E);

    scan_a<<<SCAN_B, SCAN_T, 0, stream>>>(cnt, bsum, n);
    scan_b<<<SCAN_B, SCAN_T, 0, stream>>>(cnt, bsum, rowptr, n, E);

    scatter_k<<<(E + 255) / 256, 256, 0, stream>>>(ei, rowptr, slot, ssrc, E);

    gemm1_mfma<<<(n + 127) / 128, 512, 0, stream>>>(x, W1T, att_src1, att_dst1, h1b, asrc1, adst1, n);

    agg1_k<<<(n + 3) / 4, 256, 0, stream>>>(rowptr, ssrc, asrc1, adst1, h1b, b1,
                                            W2, att_src2, att_dst2, h2b, asrc2, adst2, n);

    agg2_k<<<(n + 3) / 4, 256, 0, stream>>>(rowptr, ssrc, asrc2, adst2, h2b, b2, out, n);
}

// Round 17
// 282.465 us; speedup vs baseline: 1.1158x; 1.1158x over previous
//
#include <hip/hip_runtime.h>
#include <hip/hip_bf16.h>

#define NEG_SLOPE 0.2f

typedef __attribute__((ext_vector_type(8))) short  bf16x8;
typedef __attribute__((ext_vector_type(8))) unsigned short u16x8;
typedef __attribute__((ext_vector_type(4))) unsigned short u16x4;
typedef __attribute__((ext_vector_type(4))) float  f32x4;

static __device__ __forceinline__ ushort f2bf(float f) {
    union { float f; unsigned int u; } c; c.f = f;
    unsigned int r = c.u + 0x7fffu + ((c.u >> 16) & 1u);   // round-to-nearest-even
    return (ushort)(r >> 16);
}
static __device__ __forceinline__ float bf2f(ushort u) {
    union { unsigned int u; float f; } c; c.u = ((unsigned int)u) << 16;
    return c.f;
}

// ---------------- zero cnt ----------------
__global__ __launch_bounds__(256) void zero_k(int4* __restrict__ p, int n4)
{
    int t = blockIdx.x * 256 + threadIdx.x;
    if (t < n4) p[t] = make_int4(0, 0, 0, 0);
}

// ---------------- phase1: prep_w1 (blocks 0..127) + hist (rest), fused ----------------
__global__ __launch_bounds__(256) void phase1_k(
    const float* __restrict__ W, ushort* __restrict__ W1T,
    const int* __restrict__ ei, int* __restrict__ cnt, int* __restrict__ slot, int E)
{
    if (blockIdx.x < 128) {
        int idx = blockIdx.x * 256 + threadIdx.x;      // 32768 = 64*512 exactly
        int c = idx >> 9, k = idx & 511;
        W1T[idx] = f2bf(W[k * 64 + c]);
    } else {
        int t = (blockIdx.x - 128) * 256 + threadIdx.x;
        if (t < E) slot[t] = atomicAdd(&cnt[ei[E + t]], 1);
    }
}

#define SCAN_B 256
#define SCAN_T 256

__global__ __launch_bounds__(SCAN_T) void scan_a(const int* __restrict__ cnt, int* __restrict__ bsum, int n)
{
    __shared__ int sh[SCAN_T];
    const int tid = threadIdx.x;
    const int per = (n + SCAN_B * SCAN_T - 1) / (SCAN_B * SCAN_T);
    const int lo = (blockIdx.x * SCAN_T + tid) * per;
    const int hi = min(n, lo + per);
    int s = 0;
    for (int i = lo; i < hi; ++i) s += cnt[i];
    sh[tid] = s;
    __syncthreads();
    #pragma unroll
    for (int o = SCAN_T / 2; o; o >>= 1) {
        if (tid < o) sh[tid] += sh[tid + o];
        __syncthreads();
    }
    if (tid == 0) bsum[blockIdx.x] = sh[0];
}

__global__ __launch_bounds__(SCAN_T) void scan_b(
    const int* __restrict__ cnt, const int* __restrict__ bsum,
    int* __restrict__ rowptr, int n, int E)
{
    __shared__ int sb[SCAN_B];
    __shared__ int sh[SCAN_T];
    const int tid = threadIdx.x;
    sb[tid] = bsum[tid];
    __syncthreads();
    #pragma unroll
    for (int o = 1; o < SCAN_B; o <<= 1) {
        int v = (tid >= o) ? sb[tid - o] : 0;
        __syncthreads();
        sb[tid] += v;
        __syncthreads();
    }
    const int boff = (blockIdx.x == 0) ? 0 : sb[blockIdx.x - 1];

    const int per = (n + SCAN_B * SCAN_T - 1) / (SCAN_B * SCAN_T);
    const int lo = (blockIdx.x * SCAN_T + tid) * per;
    const int hi = min(n, lo + per);
    int s = 0;
    for (int i = lo; i < hi; ++i) s += cnt[i];
    sh[tid] = s;
    __syncthreads();
    #pragma unroll
    for (int o = 1; o < SCAN_T; o <<= 1) {
        int v = (tid >= o) ? sh[tid - o] : 0;
        __syncthreads();
        sh[tid] += v;
        __syncthreads();
    }
    int excl = boff + ((tid == 0) ? 0 : sh[tid - 1]);
    for (int i = lo; i < hi; ++i) { rowptr[i] = excl; excl += cnt[i]; }
    if (blockIdx.x == 0 && tid == 0) rowptr[n] = E;
}

__global__ __launch_bounds__(256) void scatter_k(
    const int* __restrict__ ei, const int* __restrict__ rowptr,
    const int* __restrict__ slot, int* __restrict__ ssrc, int E)
{
    int t = blockIdx.x * blockDim.x + threadIdx.x;
    if (t >= E) return;
    int d = ei[E + t];
    ssrc[rowptr[d] + slot[t]] = ei[t];
}

// ---------------- GEMM1 (R10 config) + PACKED epilogue: h1p row = [asrc bf16 x8][h1 bf16 x64]
__global__ __launch_bounds__(512, 4) void gemm1_mfma(
    const float* __restrict__ x, const ushort* __restrict__ W1T,
    const float* __restrict__ att_src, const float* __restrict__ att_dst,
    ushort* __restrict__ h1p, float* __restrict__ adst, int n)
{
    __shared__ ushort Bs[64][520];  // [col][k] bf16, padded row (1040B)
    const int t    = threadIdx.x;
    const int lane = t & 63;
    const int wv   = t >> 6;        // 0..7
    const int rb   = blockIdx.x * 128;
    const int m    = lane & 15;
    const int kg   = lane >> 4;

    // stage W1T -> Bs: 4096 chunks of 8 ushorts (16B); 8 per thread
    #pragma unroll
    for (int i = 0; i < 8; ++i) {
        int chunk = t + i * 512;        // 0..4095
        int c  = chunk >> 6;            // 64 chunks of 8 ushorts per row
        int ko = (chunk & 63) * 8;
        *(u16x8*)&Bs[c][ko] = *(const u16x8*)(W1T + c * 512 + ko);
    }

    const int arow  = rb + wv * 16 + m;
    const int arowc = min(arow, n - 1);
    const float* xp = x + (size_t)arowc * 512 + kg * 8;

    f32x4 acc[4] = {};
    __syncthreads();

    // depth-2 register prefetch, no barriers in K-loop
    float4 lo0 = *(const float4*)(xp);
    float4 hi0 = *(const float4*)(xp + 4);
    float4 lo1 = *(const float4*)(xp + 32);
    float4 hi1 = *(const float4*)(xp + 36);
    #pragma unroll
    for (int k32 = 0; k32 < 16; ++k32) {
        float4 nlo = {}, nhi = {};
        if (k32 < 14) {
            nlo = *(const float4*)(xp + (k32 + 2) * 32);
            nhi = *(const float4*)(xp + (k32 + 2) * 32 + 4);
        }
        u16x8 a;
        a[0] = f2bf(lo0.x); a[1] = f2bf(lo0.y); a[2] = f2bf(lo0.z); a[3] = f2bf(lo0.w);
        a[4] = f2bf(hi0.x); a[5] = f2bf(hi0.y); a[6] = f2bf(hi0.z); a[7] = f2bf(hi0.w);
        bf16x8 af = *(bf16x8*)&a;
        #pragma unroll
        for (int t4 = 0; t4 < 4; ++t4) {
            bf16x8 bfr = *(const bf16x8*)&Bs[t4 * 16 + m][k32 * 32 + kg * 8];
            acc[t4] = __builtin_amdgcn_mfma_f32_16x16x32_bf16(af, bfr, acc[t4], 0, 0, 0);
        }
        lo0 = lo1; hi0 = hi1; lo1 = nlo; hi1 = nhi;
    }

    // epilogue: C/D col=m, row=kg*4+i; packed write + fused per-head att reductions
    #pragma unroll
    for (int t4 = 0; t4 < 4; ++t4) {
        const float as_w = att_src[t4 * 16 + m];
        const float ad_w = att_dst[t4 * 16 + m];
        #pragma unroll
        for (int i = 0; i < 4; ++i) {
            int gr = rb + wv * 16 + kg * 4 + i;
            float v = acc[t4][i];
            float ps = v * as_w, pd = v * ad_w;
            ps += __shfl_xor(ps, 1); pd += __shfl_xor(pd, 1);
            ps += __shfl_xor(ps, 2); pd += __shfl_xor(pd, 2);
            ps += __shfl_xor(ps, 4); pd += __shfl_xor(pd, 4);
            if (gr < n) {
                h1p[(size_t)gr * 72 + 8 + t4 * 16 + m] = f2bf(v);
                if ((m & 7) == 0) {
                    int h = t4 * 2 + (m >> 3);
                    h1p[(size_t)gr * 72 + h] = f2bf(ps);   // asrc packed, bf16
                    adst[gr * 8 + h] = pd;                 // adst stays f32 (wave-uniform read)
                }
            }
        }
    }
}

// ---------------- layer1 aggregate + ELU + GEMM2 + att2 (packed h1p reads) ----------------
__global__ __launch_bounds__(256) void agg1_k(
    const int* __restrict__ rowptr, const int* __restrict__ ssrc,
    const float* __restrict__ adst1,
    const ushort* __restrict__ h1p, const float* __restrict__ b1,
    const float* __restrict__ W2, const float* __restrict__ att_src2, const float* __restrict__ att_dst2,
    ushort* __restrict__ h2b, float* __restrict__ asrc2, float* __restrict__ adst2, int n)
{
    __shared__ float Ws2[64 * 17];
    __shared__ float sv[4][64];
    const int t = threadIdx.x;
    #pragma unroll
    for (int k = 0; k < 4; ++k) {
        int idx = t + k * 256;
        Ws2[(idx >> 4) * 17 + (idx & 15)] = W2[idx];
    }
    __syncthreads();

    const int wv = t >> 6;
    const int j  = t & 63;
    const int g  = j >> 3;
    const int h  = j & 7;
    const int node = blockIdx.x * 4 + wv;
    const bool active = node < n;

    if (active) {
        const int d = node;
        const int start = rowptr[d], end = rowptr[d + 1];
        const float adsth = adst1[d * 8 + h];
        float acc0[8] = {}, acc1[8] = {};
        float dsum0 = 0.f, dsum1 = 0.f;
        for (int base = start - 1; base < end; base += 16) {
            int i0 = base + g;
            int i1 = i0 + 8;
            if (i0 < end) {
                int s = (i0 < start) ? d : ssrc[i0];
                float e = bf2f(h1p[(size_t)s * 72 + h]) + adsth;
                e = e > 0.f ? e : NEG_SLOPE * e;
                float ex = __expf(e);
                dsum0 += ex;
                u16x8 hv = *(const u16x8*)(h1p + (size_t)s * 72 + 8 + h * 8);
                #pragma unroll
                for (int c = 0; c < 8; ++c) acc0[c] += ex * bf2f(hv[c]);
            }
            if (i1 < end) {
                int s = ssrc[i1];
                float e = bf2f(h1p[(size_t)s * 72 + h]) + adsth;
                e = e > 0.f ? e : NEG_SLOPE * e;
                float ex = __expf(e);
                dsum1 += ex;
                u16x8 hv = *(const u16x8*)(h1p + (size_t)s * 72 + 8 + h * 8);
                #pragma unroll
                for (int c = 0; c < 8; ++c) acc1[c] += ex * bf2f(hv[c]);
            }
        }
        float dsum = dsum0 + dsum1;
        float acc[8];
        #pragma unroll
        for (int c = 0; c < 8; ++c) acc[c] = acc0[c] + acc1[c];
        #pragma unroll
        for (int o = 8; o < 64; o <<= 1) {
            dsum += __shfl_xor(dsum, o);
            #pragma unroll
            for (int c = 0; c < 8; ++c) acc[c] += __shfl_xor(acc[c], o);
        }
        if (g == 0) {
            float den = dsum + 1e-16f;
            #pragma unroll
            for (int c = 0; c < 8; ++c) {
                float v = acc[c] / den + b1[h * 8 + c];
                v = v > 0.f ? v : (__expf(v) - 1.f);   // ELU
                sv[wv][h * 8 + c] = v;
            }
        }
    }
    __syncthreads();

    if (active) {
        const int c = j & 15, q = j >> 4;
        float p = 0.f;
        #pragma unroll
        for (int r = 0; r < 16; ++r)
            p += sv[wv][q * 16 + r] * Ws2[(q * 16 + r) * 17 + c];
        p += __shfl_xor(p, 16);
        p += __shfl_xor(p, 32);
        if (j < 16) h2b[(size_t)node * 16 + j] = f2bf(p);
        float as2 = p * att_src2[c];
        float ad2 = p * att_dst2[c];
        #pragma unroll
        for (int o = 1; o < 16; o <<= 1) { as2 += __shfl_xor(as2, o, 16); ad2 += __shfl_xor(ad2, o, 16); }
        if (j == 0) { asrc2[node] = as2; adst2[node] = ad2; }
    }
}

// ---------------- layer2 aggregate + log_softmax ----------------
__global__ __launch_bounds__(256) void agg2_k(
    const int* __restrict__ rowptr, const int* __restrict__ ssrc,
    const float* __restrict__ asrc2, const float* __restrict__ adst2,
    const ushort* __restrict__ h2b, const float* __restrict__ b2,
    float* __restrict__ out, int n)
{
    const int t = threadIdx.x;
    const int node = blockIdx.x * 4 + (t >> 6);
    if (node >= n) return;
    const int j = t & 63;
    const int g = j >> 2;
    const int q = j & 3;
    const int d = node;
    const int start = rowptr[d], end = rowptr[d + 1];
    const float adst_d = adst2[d];

    float acc0[4] = {}, acc1[4] = {};
    float dsum0 = 0.f, dsum1 = 0.f;
    for (int base = start - 1; base < end; base += 32) {
        int i0 = base + g;
        int i1 = i0 + 16;
        if (i0 < end) {
            int s = (i0 < start) ? d : ssrc[i0];
            float e = asrc2[s] + adst_d;
            e = e > 0.f ? e : NEG_SLOPE * e;
            float ex = __expf(e);
            dsum0 += ex;
            u16x4 hv = *(const u16x4*)(h2b + (size_t)s * 16 + q * 4);
            #pragma unroll
            for (int c = 0; c < 4; ++c) acc0[c] += ex * bf2f(hv[c]);
        }
        if (i1 < end) {
            int s = ssrc[i1];
            float e = asrc2[s] + adst_d;
            e = e > 0.f ? e : NEG_SLOPE * e;
            float ex = __expf(e);
            dsum1 += ex;
            u16x4 hv = *(const u16x4*)(h2b + (size_t)s * 16 + q * 4);
            #pragma unroll
            for (int c = 0; c < 4; ++c) acc1[c] += ex * bf2f(hv[c]);
        }
    }
    float dsum = dsum0 + dsum1;
    float acc[4];
    #pragma unroll
    for (int c = 0; c < 4; ++c) acc[c] = acc0[c] + acc1[c];
    #pragma unroll
    for (int o = 4; o < 64; o <<= 1) {
        dsum += __shfl_xor(dsum, o);
        #pragma unroll
        for (int c = 0; c < 4; ++c) acc[c] += __shfl_xor(acc[c], o);
    }

    const float den = dsum + 1e-16f;
    float v[4];
    float m = -1e30f;
    #pragma unroll
    for (int c = 0; c < 4; ++c) {
        v[c] = acc[c] / den + b2[q * 4 + c];
        m = fmaxf(m, v[c]);
    }
    m = fmaxf(m, __shfl_xor(m, 1));
    m = fmaxf(m, __shfl_xor(m, 2));
    float s2 = 0.f;
    #pragma unroll
    for (int c = 0; c < 4; ++c) s2 += __expf(v[c] - m);
    s2 += __shfl_xor(s2, 1);
    s2 += __shfl_xor(s2, 2);
    const float lse = m + logf(s2);
    if (j < 4) {
        float4 o4 = make_float4(v[0] - lse, v[1] - lse, v[2] - lse, v[3] - lse);
        *(float4*)(out + (size_t)d * 16 + q * 4) = o4;
    }
}

static inline size_t align_up(size_t v, size_t a) { return (v + a - 1) & ~(a - 1); }

extern "C" void kernel_launch(void* const* d_in, const int* in_sizes, int n_in,
                              void* d_out, int out_size, void* d_ws, size_t ws_size,
                              hipStream_t stream) {
    const float* x        = (const float*)d_in[0];
    const int*   ei       = (const int*)d_in[1];
    const float* W1       = (const float*)d_in[2];
    const float* att_src1 = (const float*)d_in[3];
    const float* att_dst1 = (const float*)d_in[4];
    const float* b1       = (const float*)d_in[5];
    const float* W2       = (const float*)d_in[6];
    const float* att_src2 = (const float*)d_in[7];
    const float* att_dst2 = (const float*)d_in[8];
    const float* b2       = (const float*)d_in[9];
    float* out = (float*)d_out;

    const int n = in_sizes[0] / 512;
    const int E = in_sizes[1] / 2;

    // 64B-aligned workspace layout
    char* base = (char*)d_ws;
    size_t off = 0;
    ushort* h1p   = (ushort*)(base + off); off = align_up(off + (size_t)144 * n, 64);  // packed [asrc x8 | h1 x64] bf16
    ushort* h2b   = (ushort*)(base + off); off = align_up(off + (size_t)32 * n, 64);
    float*  adst1 = (float*) (base + off); off = align_up(off + (size_t)32 * n, 64);
    float*  asrc2 = (float*) (base + off); off = align_up(off + (size_t)4 * n, 64);
    float*  adst2 = (float*) (base + off); off = align_up(off + (size_t)4 * n, 64);
    ushort* W1T   = (ushort*)(base + off); off = align_up(off + (size_t)65536, 64);
    int*    rowptr= (int*)   (base + off); off = align_up(off + (size_t)4 * (n + 1), 64);
    int*    cnt   = (int*)   (base + off); off = align_up(off + (size_t)4 * n, 64);
    int*    bsum  = (int*)   (base + off); off = align_up(off + (size_t)1024, 64);
    int*    slot  = (int*)   (base + off); off = align_up(off + (size_t)4 * E, 64);
    int*    ssrc  = (int*)   (base + off);

    const int n4 = (n + 3) / 4;
    zero_k<<<(n4 + 255) / 256, 256, 0, stream>>>((int4*)cnt, n4);

    phase1_k<<<128 + (E + 255) / 256, 256, 0, stream>>>(W1, W1T, ei, cnt, slot, E);

    scan_a<<<SCAN_B, SCAN_T, 0, stream>>>(cnt, bsum, n);
    scan_b<<<SCAN_B, SCAN_T, 0, stream>>>(cnt, bsum, rowptr, n, E);

    scatter_k<<<(E + 255) / 256, 256, 0, stream>>>(ei, rowptr, slot, ssrc, E);

    gemm1_mfma<<<(n + 127) / 128, 512, 0, stream>>>(x, W1T, att_src1, att_dst1, h1p, adst1, n);

    agg1_k<<<(n + 3) / 4, 256, 0, stream>>>(rowptr, ssrc, adst1, h1p, b1,
                                            W2, att_src2, att_dst2, h2b, asrc2, adst2, n);

    agg2_k<<<(n + 3) / 4, 256, 0, stream>>>(rowptr, ssrc, asrc2, adst2, h2b, b2, out, n);
}

// Round 18
// 267.301 us; speedup vs baseline: 1.1791x; 1.0567x over previous
//
#include <hip/hip_runtime.h>
#include <hip/hip_bf16.h>

#define NEG_SLOPE 0.2f

typedef __attribute__((ext_vector_type(8))) short  bf16x8;
typedef __attribute__((ext_vector_type(8))) unsigned short u16x8;
typedef __attribute__((ext_vector_type(4))) unsigned short u16x4;
typedef __attribute__((ext_vector_type(4))) float  f32x4;

static __device__ __forceinline__ ushort f2bf(float f) {
    union { float f; unsigned int u; } c; c.f = f;
    unsigned int r = c.u + 0x7fffu + ((c.u >> 16) & 1u);   // round-to-nearest-even
    return (ushort)(r >> 16);
}
static __device__ __forceinline__ float bf2f(ushort u) {
    union { unsigned int u; float f; } c; c.u = ((unsigned int)u) << 16;
    return c.f;
}

// ---------------- zero cnt ----------------
__global__ __launch_bounds__(256) void zero_k(int4* __restrict__ p, int n4)
{
    int t = blockIdx.x * 256 + threadIdx.x;
    if (t < n4) p[t] = make_int4(0, 0, 0, 0);
}

// ---------------- phase1: prep_w1 (blocks 0..127) + hist (rest), fused ----------------
__global__ __launch_bounds__(256) void phase1_k(
    const float* __restrict__ W, ushort* __restrict__ W1T,
    const int* __restrict__ ei, int* __restrict__ cnt, int* __restrict__ slot, int E)
{
    if (blockIdx.x < 128) {
        int idx = blockIdx.x * 256 + threadIdx.x;      // 32768 = 64*512 exactly
        int c = idx >> 9, k = idx & 511;
        W1T[idx] = f2bf(W[k * 64 + c]);
    } else {
        int t = (blockIdx.x - 128) * 256 + threadIdx.x;
        if (t < E) slot[t] = atomicAdd(&cnt[ei[E + t]], 1);
    }
}

#define SCAN_B 256
#define SCAN_T 256

__global__ __launch_bounds__(SCAN_T) void scan_a(const int* __restrict__ cnt, int* __restrict__ bsum, int n)
{
    __shared__ int sh[SCAN_T];
    const int tid = threadIdx.x;
    const int per = (n + SCAN_B * SCAN_T - 1) / (SCAN_B * SCAN_T);
    const int lo = (blockIdx.x * SCAN_T + tid) * per;
    const int hi = min(n, lo + per);
    int s = 0;
    for (int i = lo; i < hi; ++i) s += cnt[i];
    sh[tid] = s;
    __syncthreads();
    #pragma unroll
    for (int o = SCAN_T / 2; o; o >>= 1) {
        if (tid < o) sh[tid] += sh[tid + o];
        __syncthreads();
    }
    if (tid == 0) bsum[blockIdx.x] = sh[0];
}

__global__ __launch_bounds__(SCAN_T) void scan_b(
    const int* __restrict__ cnt, const int* __restrict__ bsum,
    int* __restrict__ rowptr, int n, int E)
{
    __shared__ int sb[SCAN_B];
    __shared__ int sh[SCAN_T];
    const int tid = threadIdx.x;
    sb[tid] = bsum[tid];
    __syncthreads();
    #pragma unroll
    for (int o = 1; o < SCAN_B; o <<= 1) {
        int v = (tid >= o) ? sb[tid - o] : 0;
        __syncthreads();
        sb[tid] += v;
        __syncthreads();
    }
    const int boff = (blockIdx.x == 0) ? 0 : sb[blockIdx.x - 1];

    const int per = (n + SCAN_B * SCAN_T - 1) / (SCAN_B * SCAN_T);
    const int lo = (blockIdx.x * SCAN_T + tid) * per;
    const int hi = min(n, lo + per);
    int s = 0;
    for (int i = lo; i < hi; ++i) s += cnt[i];
    sh[tid] = s;
    __syncthreads();
    #pragma unroll
    for (int o = 1; o < SCAN_T; o <<= 1) {
        int v = (tid >= o) ? sh[tid - o] : 0;
        __syncthreads();
        sh[tid] += v;
        __syncthreads();
    }
    int excl = boff + ((tid == 0) ? 0 : sh[tid - 1]);
    for (int i = lo; i < hi; ++i) { rowptr[i] = excl; excl += cnt[i]; }
    if (blockIdx.x == 0 && tid == 0) rowptr[n] = E;
}

__global__ __launch_bounds__(256) void scatter_k(
    const int* __restrict__ ei, const int* __restrict__ rowptr,
    const int* __restrict__ slot, int* __restrict__ ssrc, int E)
{
    int t = blockIdx.x * blockDim.x + threadIdx.x;
    if (t >= E) return;
    int d = ei[E + t];
    ssrc[rowptr[d] + slot[t]] = ei[t];
}

// ---------------- GEMM1 via bf16 MFMA: 8 waves, clean staging, barrier-free K (best config) -
__global__ __launch_bounds__(512, 4) void gemm1_mfma(
    const float* __restrict__ x, const ushort* __restrict__ W1T,
    const float* __restrict__ att_src, const float* __restrict__ att_dst,
    ushort* __restrict__ h1b, float* __restrict__ asrc, float* __restrict__ adst, int n)
{
    __shared__ ushort Bs[64][520];  // [col][k] bf16, padded row (1040B)
    const int t    = threadIdx.x;
    const int lane = t & 63;
    const int wv   = t >> 6;        // 0..7
    const int rb   = blockIdx.x * 128;
    const int m    = lane & 15;
    const int kg   = lane >> 4;

    // stage W1T -> Bs: 4096 chunks of 8 ushorts (16B); 8 per thread
    #pragma unroll
    for (int i = 0; i < 8; ++i) {
        int chunk = t + i * 512;        // 0..4095
        int c  = chunk >> 6;            // 64 chunks of 8 ushorts per row
        int ko = (chunk & 63) * 8;
        *(u16x8*)&Bs[c][ko] = *(const u16x8*)(W1T + c * 512 + ko);
    }

    const int arow  = rb + wv * 16 + m;
    const int arowc = min(arow, n - 1);
    const float* xp = x + (size_t)arowc * 512 + kg * 8;

    f32x4 acc[4] = {};
    __syncthreads();

    // depth-2 register prefetch, no barriers in K-loop
    float4 lo0 = *(const float4*)(xp);
    float4 hi0 = *(const float4*)(xp + 4);
    float4 lo1 = *(const float4*)(xp + 32);
    float4 hi1 = *(const float4*)(xp + 36);
    #pragma unroll
    for (int k32 = 0; k32 < 16; ++k32) {
        float4 nlo = {}, nhi = {};
        if (k32 < 14) {
            nlo = *(const float4*)(xp + (k32 + 2) * 32);
            nhi = *(const float4*)(xp + (k32 + 2) * 32 + 4);
        }
        u16x8 a;
        a[0] = f2bf(lo0.x); a[1] = f2bf(lo0.y); a[2] = f2bf(lo0.z); a[3] = f2bf(lo0.w);
        a[4] = f2bf(hi0.x); a[5] = f2bf(hi0.y); a[6] = f2bf(hi0.z); a[7] = f2bf(hi0.w);
        bf16x8 af = *(bf16x8*)&a;
        #pragma unroll
        for (int t4 = 0; t4 < 4; ++t4) {
            bf16x8 bfr = *(const bf16x8*)&Bs[t4 * 16 + m][k32 * 32 + kg * 8];
            acc[t4] = __builtin_amdgcn_mfma_f32_16x16x32_bf16(af, bfr, acc[t4], 0, 0, 0);
        }
        lo0 = lo1; hi0 = hi1; lo1 = nlo; hi1 = nhi;
    }

    // epilogue: C/D col=m, row=kg*4+i; fused per-head att reductions
    #pragma unroll
    for (int t4 = 0; t4 < 4; ++t4) {
        const float as_w = att_src[t4 * 16 + m];
        const float ad_w = att_dst[t4 * 16 + m];
        #pragma unroll
        for (int i = 0; i < 4; ++i) {
            int gr = rb + wv * 16 + kg * 4 + i;
            float v = acc[t4][i];
            float ps = v * as_w, pd = v * ad_w;
            ps += __shfl_xor(ps, 1); pd += __shfl_xor(pd, 1);
            ps += __shfl_xor(ps, 2); pd += __shfl_xor(pd, 2);
            ps += __shfl_xor(ps, 4); pd += __shfl_xor(pd, 4);
            if (gr < n) {
                h1b[(size_t)gr * 64 + t4 * 16 + m] = f2bf(v);
                if ((m & 7) == 0) {
                    int h = t4 * 2 + (m >> 3);
                    asrc[gr * 8 + h] = ps;
                    adst[gr * 8 + h] = pd;
                }
            }
        }
    }
}

// ---------------- layer1 aggregate + ELU + GEMM2 + att2 ----------------
__global__ __launch_bounds__(256) void agg1_k(
    const int* __restrict__ rowptr, const int* __restrict__ ssrc,
    const float* __restrict__ asrc1, const float* __restrict__ adst1,
    const ushort* __restrict__ h1b, const float* __restrict__ b1,
    const float* __restrict__ W2, const float* __restrict__ att_src2, const float* __restrict__ att_dst2,
    ushort* __restrict__ h2b, float* __restrict__ asrc2, float* __restrict__ adst2, int n)
{
    __shared__ float Ws2[64 * 17];
    __shared__ float sv[4][64];
    const int t = threadIdx.x;
    #pragma unroll
    for (int k = 0; k < 4; ++k) {
        int idx = t + k * 256;
        Ws2[(idx >> 4) * 17 + (idx & 15)] = W2[idx];
    }
    __syncthreads();

    const int wv = t >> 6;
    const int j  = t & 63;
    const int g  = j >> 3;
    const int h  = j & 7;
    const int node = blockIdx.x * 4 + wv;
    const bool active = node < n;

    if (active) {
        const int d = node;
        const int start = rowptr[d], end = rowptr[d + 1];
        const float adsth = adst1[d * 8 + h];
        float acc0[8] = {}, acc1[8] = {};
        float dsum0 = 0.f, dsum1 = 0.f;
        for (int base = start - 1; base < end; base += 16) {
            int i0 = base + g;
            int i1 = i0 + 8;
            if (i0 < end) {
                int s = (i0 < start) ? d : ssrc[i0];
                float e = asrc1[s * 8 + h] + adsth;
                e = e > 0.f ? e : NEG_SLOPE * e;
                float ex = __expf(e);
                dsum0 += ex;
                u16x8 hv = *(const u16x8*)(h1b + (size_t)s * 64 + h * 8);
                #pragma unroll
                for (int c = 0; c < 8; ++c) acc0[c] += ex * bf2f(hv[c]);
            }
            if (i1 < end) {
                int s = ssrc[i1];
                float e = asrc1[s * 8 + h] + adsth;
                e = e > 0.f ? e : NEG_SLOPE * e;
                float ex = __expf(e);
                dsum1 += ex;
                u16x8 hv = *(const u16x8*)(h1b + (size_t)s * 64 + h * 8);
                #pragma unroll
                for (int c = 0; c < 8; ++c) acc1[c] += ex * bf2f(hv[c]);
            }
        }
        float dsum = dsum0 + dsum1;
        float acc[8];
        #pragma unroll
        for (int c = 0; c < 8; ++c) acc[c] = acc0[c] + acc1[c];
        #pragma unroll
        for (int o = 8; o < 64; o <<= 1) {
            dsum += __shfl_xor(dsum, o);
            #pragma unroll
            for (int c = 0; c < 8; ++c) acc[c] += __shfl_xor(acc[c], o);
        }
        if (g == 0) {
            float den = dsum + 1e-16f;
            #pragma unroll
            for (int c = 0; c < 8; ++c) {
                float v = acc[c] / den + b1[h * 8 + c];
                v = v > 0.f ? v : (__expf(v) - 1.f);   // ELU
                sv[wv][h * 8 + c] = v;
            }
        }
    }
    __syncthreads();

    if (active) {
        const int c = j & 15, q = j >> 4;
        float p = 0.f;
        #pragma unroll
        for (int r = 0; r < 16; ++r)
            p += sv[wv][q * 16 + r] * Ws2[(q * 16 + r) * 17 + c];
        p += __shfl_xor(p, 16);
        p += __shfl_xor(p, 32);
        if (j < 16) h2b[(size_t)node * 16 + j] = f2bf(p);
        float as2 = p * att_src2[c];
        float ad2 = p * att_dst2[c];
        #pragma unroll
        for (int o = 1; o < 16; o <<= 1) { as2 += __shfl_xor(as2, o, 16); ad2 += __shfl_xor(ad2, o, 16); }
        if (j == 0) { asrc2[node] = as2; adst2[node] = ad2; }
    }
}

// ---------------- layer2 aggregate + log_softmax ----------------
__global__ __launch_bounds__(256) void agg2_k(
    const int* __restrict__ rowptr, const int* __restrict__ ssrc,
    const float* __restrict__ asrc2, const float* __restrict__ adst2,
    const ushort* __restrict__ h2b, const float* __restrict__ b2,
    float* __restrict__ out, int n)
{
    const int t = threadIdx.x;
    const int node = blockIdx.x * 4 + (t >> 6);
    if (node >= n) return;
    const int j = t & 63;
    const int g = j >> 2;
    const int q = j & 3;
    const int d = node;
    const int start = rowptr[d], end = rowptr[d + 1];
    const float adst_d = adst2[d];

    float acc0[4] = {}, acc1[4] = {};
    float dsum0 = 0.f, dsum1 = 0.f;
    for (int base = start - 1; base < end; base += 32) {
        int i0 = base + g;
        int i1 = i0 + 16;
        if (i0 < end) {
            int s = (i0 < start) ? d : ssrc[i0];
            float e = asrc2[s] + adst_d;
            e = e > 0.f ? e : NEG_SLOPE * e;
            float ex = __expf(e);
            dsum0 += ex;
            u16x4 hv = *(const u16x4*)(h2b + (size_t)s * 16 + q * 4);
            #pragma unroll
            for (int c = 0; c < 4; ++c) acc0[c] += ex * bf2f(hv[c]);
        }
        if (i1 < end) {
            int s = ssrc[i1];
            float e = asrc2[s] + adst_d;
            e = e > 0.f ? e : NEG_SLOPE * e;
            float ex = __expf(e);
            dsum1 += ex;
            u16x4 hv = *(const u16x4*)(h2b + (size_t)s * 16 + q * 4);
            #pragma unroll
            for (int c = 0; c < 4; ++c) acc1[c] += ex * bf2f(hv[c]);
        }
    }
    float dsum = dsum0 + dsum1;
    float acc[4];
    #pragma unroll
    for (int c = 0; c < 4; ++c) acc[c] = acc0[c] + acc1[c];
    #pragma unroll
    for (int o = 4; o < 64; o <<= 1) {
        dsum += __shfl_xor(dsum, o);
        #pragma unroll
        for (int c = 0; c < 4; ++c) acc[c] += __shfl_xor(acc[c], o);
    }

    const float den = dsum + 1e-16f;
    float v[4];
    float m = -1e30f;
    #pragma unroll
    for (int c = 0; c < 4; ++c) {
        v[c] = acc[c] / den + b2[q * 4 + c];
        m = fmaxf(m, v[c]);
    }
    m = fmaxf(m, __shfl_xor(m, 1));
    m = fmaxf(m, __shfl_xor(m, 2));
    float s2 = 0.f;
    #pragma unroll
    for (int c = 0; c < 4; ++c) s2 += __expf(v[c] - m);
    s2 += __shfl_xor(s2, 1);
    s2 += __shfl_xor(s2, 2);
    const float lse = m + logf(s2);
    if (j < 4) {
        float4 o4 = make_float4(v[0] - lse, v[1] - lse, v[2] - lse, v[3] - lse);
        *(float4*)(out + (size_t)d * 16 + q * 4) = o4;
    }
}

static inline size_t align_up(size_t v, size_t a) { return (v + a - 1) & ~(a - 1); }

extern "C" void kernel_launch(void* const* d_in, const int* in_sizes, int n_in,
                              void* d_out, int out_size, void* d_ws, size_t ws_size,
                              hipStream_t stream) {
    const float* x        = (const float*)d_in[0];
    const int*   ei       = (const int*)d_in[1];
    const float* W1       = (const float*)d_in[2];
    const float* att_src1 = (const float*)d_in[3];
    const float* att_dst1 = (const float*)d_in[4];
    const float* b1       = (const float*)d_in[5];
    const float* W2       = (const float*)d_in[6];
    const float* att_src2 = (const float*)d_in[7];
    const float* att_dst2 = (const float*)d_in[8];
    const float* b2       = (const float*)d_in[9];
    float* out = (float*)d_out;

    const int n = in_sizes[0] / 512;
    const int E = in_sizes[1] / 2;

    // 64B-aligned workspace layout
    char* base = (char*)d_ws;
    size_t off = 0;
    ushort* h1b   = (ushort*)(base + off); off = align_up(off + (size_t)128 * n, 64);
    ushort* h2b   = (ushort*)(base + off); off = align_up(off + (size_t)32 * n, 64);
    float*  asrc1 = (float*) (base + off); off = align_up(off + (size_t)32 * n, 64);
    float*  adst1 = (float*) (base + off); off = align_up(off + (size_t)32 * n, 64);
    float*  asrc2 = (float*) (base + off); off = align_up(off + (size_t)4 * n, 64);
    float*  adst2 = (float*) (base + off); off = align_up(off + (size_t)4 * n, 64);
    ushort* W1T   = (ushort*)(base + off); off = align_up(off + (size_t)65536, 64);
    int*    rowptr= (int*)   (base + off); off = align_up(off + (size_t)4 * (n + 1), 64);
    int*    cnt   = (int*)   (base + off); off = align_up(off + (size_t)4 * n, 64);
    int*    bsum  = (int*)   (base + off); off = align_up(off + (size_t)1024, 64);
    int*    slot  = (int*)   (base + off); off = align_up(off + (size_t)4 * E, 64);
    int*    ssrc  = (int*)   (base + off);

    const int n4 = (n + 3) / 4;
    zero_k<<<(n4 + 255) / 256, 256, 0, stream>>>((int4*)cnt, n4);

    phase1_k<<<128 + (E + 255) / 256, 256, 0, stream>>>(W1, W1T, ei, cnt, slot, E);

    scan_a<<<SCAN_B, SCAN_T, 0, stream>>>(cnt, bsum, n);
    scan_b<<<SCAN_B, SCAN_T, 0, stream>>>(cnt, bsum, rowptr, n, E);

    scatter_k<<<(E + 255) / 256, 256, 0, stream>>>(ei, rowptr, slot, ssrc, E);

    gemm1_mfma<<<(n + 127) / 128, 512, 0, stream>>>(x, W1T, att_src1, att_dst1, h1b, asrc1, adst1, n);

    agg1_k<<<(n + 3) / 4, 256, 0, stream>>>(rowptr, ssrc, asrc1, adst1, h1b, b1,
                                            W2, att_src2, att_dst2, h2b, asrc2, adst2, n);

    agg2_k<<<(n + 3) / 4, 256, 0, stream>>>(rowptr, ssrc, asrc2, adst2, h2b, b2, out, n);
}